// Round 4
// baseline (297.980 us; speedup 1.0000x reference)
//
#include <hip/hip_runtime.h>

#define NN 100000
#define NE 800000

typedef short bf16x8 __attribute__((ext_vector_type(8)));
typedef float f32x4 __attribute__((ext_vector_type(4)));

__device__ __forceinline__ float wave_reduce_sum(float v) {
    #pragma unroll
    for (int o = 32; o > 0; o >>= 1) v += __shfl_down(v, o, 64);
    return v; // valid in lane 0
}

__device__ __forceinline__ unsigned short f2bf(float f) {
    unsigned u = __float_as_uint(f);
    unsigned r = (u + 0x7FFFu + ((u >> 16) & 1u)) >> 16;
    return (unsigned short)r;
}
__device__ __forceinline__ float bf2f(unsigned short b) {
    return __uint_as_float(((unsigned)b) << 16);
}

// cb layout (floats): [0..27] vs1(k*4+h)  [28..55] vd1  [56..59] c1[h]  [60] c2
//                     [64..319] was2 = W2@as2   [320..575] wad2 = W2@ad2
__global__ void k_pre(const float* __restrict__ W1, const float* __restrict__ as1,
                      const float* __restrict__ ad1,
                      const float* __restrict__ We1, const float* __restrict__ ae1,
                      const float* __restrict__ We2, const float* __restrict__ ae2,
                      const float* __restrict__ W2, const float* __restrict__ as2,
                      const float* __restrict__ ad2,
                      float* __restrict__ cb, unsigned short* __restrict__ W2fr) {
    int t = threadIdx.x;
    if (blockIdx.x == 0) {
        if (t < 28) {
            int k = t >> 2, h = t & 3;
            float s = 0.f, d = 0.f;
            for (int c = 0; c < 64; ++c) {
                float w = W1[k * 256 + h * 64 + c];
                s += w * as1[h * 64 + c];
                d += w * ad1[h * 64 + c];
            }
            cb[t] = s; cb[28 + t] = d;
        } else if (t < 32) {
            int h = t - 28;
            float s = 0.f;
            for (int c = 0; c < 64; ++c) s += We1[h * 64 + c] * ae1[h * 64 + c];
            cb[56 + h] = s;
        } else if (t == 32) {
            float s = 0.f;
            for (int c = 0; c < 64; ++c) s += We2[c] * ae2[c];
            cb[60] = s;
        }
        float s = 0.f, d = 0.f;
        for (int j = 0; j < 64; ++j) {
            float w = W2[t * 64 + j];
            s += w * as2[j];
            d += w * ad2[j];
        }
        cb[64 + t] = s;
        cb[320 + t] = d;
    } else {
        int o = (blockIdx.x - 1) * 256 + t;        // 0..16383
        int i = o & 7, l = (o >> 3) & 63, ct = (o >> 9) & 3, ks = o >> 11;
        int k = ks * 32 + ((l >> 4) * 8) + i;
        int col = ct * 16 + (l & 15);
        W2fr[o] = f2bf(W2[k * 64 + col]);
    }
}

// per-node conv1 attention coefficients via folded 7x4 tables
__global__ void k_node1(const float* __restrict__ x, const float* __restrict__ cb,
                        float* __restrict__ a_src1, float* __restrict__ a_dst1) {
    int n = blockIdx.x * 256 + threadIdx.x;
    if (n >= NN) return;
    float xv[7];
    #pragma unroll
    for (int k = 0; k < 7; ++k) xv[k] = x[n * 7 + k];
    float s[4] = {0.f, 0.f, 0.f, 0.f}, d[4] = {0.f, 0.f, 0.f, 0.f};
    #pragma unroll
    for (int k = 0; k < 7; ++k)
        #pragma unroll
        for (int h = 0; h < 4; ++h) {
            s[h] += xv[k] * cb[k * 4 + h];
            d[h] += xv[k] * cb[28 + k * 4 + h];
        }
    *(float4*)(a_src1 + n * 4) = make_float4(s[0], s[1], s[2], s[3]);
    *(float4*)(a_dst1 + n * 4) = make_float4(d[0], d[1], d[2], d[3]);
}

__global__ void k_hist(const int* __restrict__ dst, int* __restrict__ hist) {
    int e0 = (blockIdx.x * 256 + threadIdx.x) * 4;
    if (e0 >= NE) return;
    int4 d = *(const int4*)(dst + e0);
    atomicAdd(&hist[d.x], 1);
    atomicAdd(&hist[d.y], 1);
    atomicAdd(&hist[d.z], 1);
    atomicAdd(&hist[d.w], 1);
}

// --- 3-phase parallel exclusive scan over hist[NN] -> offs[NN+1], cursor[NN] ---
__global__ __launch_bounds__(1024) void k_scanA(const int* __restrict__ hist,
                                                int* __restrict__ bsum) {
    __shared__ int ws[16];
    int i = blockIdx.x * 1024 + threadIdx.x;
    int lane = threadIdx.x & 63, wid = threadIdx.x >> 6;
    int v = (i < NN) ? hist[i] : 0;
    #pragma unroll
    for (int o = 32; o; o >>= 1) v += __shfl_down(v, o, 64);
    if (lane == 0) ws[wid] = v;
    __syncthreads();
    if (wid == 0) {
        int u = (lane < 16) ? ws[lane] : 0;
        #pragma unroll
        for (int o = 8; o; o >>= 1) u += __shfl_down(u, o, 64);
        if (lane == 0) bsum[blockIdx.x] = u;
    }
}

__global__ void k_scanB(const int* __restrict__ bsum, int* __restrict__ bexcl) {
    __shared__ int w0tot;
    int t = threadIdx.x, lane = t & 63, wid = t >> 6;
    int v = (t < 98) ? bsum[t] : 0;
    int s = v;
    #pragma unroll
    for (int d = 1; d < 64; d <<= 1) { int u = __shfl_up(s, d, 64); if (lane >= d) s += u; }
    if (t == 63) w0tot = s;
    __syncthreads();
    if (wid == 1) s += w0tot;
    if (t < 98) bexcl[t] = s - v;
}

__global__ __launch_bounds__(1024) void k_scanC(const int* __restrict__ hist,
                                                const int* __restrict__ bexcl,
                                                int* __restrict__ offs,
                                                int* __restrict__ cursor) {
    __shared__ int ws[16];
    int b = blockIdx.x;
    int i = b * 1024 + threadIdx.x;
    int lane = threadIdx.x & 63, wid = threadIdx.x >> 6;
    int v = (i < NN) ? hist[i] : 0;
    int s = v;
    #pragma unroll
    for (int d = 1; d < 64; d <<= 1) { int u = __shfl_up(s, d, 64); if (lane >= d) s += u; }
    if (lane == 63) ws[wid] = s;
    __syncthreads();
    if (wid == 0) {
        int u2 = (lane < 16) ? ws[lane] : 0;
        #pragma unroll
        for (int d = 1; d < 16; d <<= 1) { int uu = __shfl_up(u2, d, 64); if (lane >= d) u2 += uu; }
        if (lane < 16) ws[lane] = u2;
    }
    __syncthreads();
    int incl = s + (wid ? ws[wid - 1] : 0) + bexcl[b];
    if (i < NN) { offs[i + 1] = incl; cursor[i] = incl - v; }
    if (i == 0) offs[0] = 0;
}

// scatter into dst-sorted order + fused conv1 edge-weight computation
// es_se[pos] = (src, ea_bits) packed 8B
__global__ void k_scatter(const int* __restrict__ src, const int* __restrict__ dst,
                          const float* __restrict__ ea,
                          const float* __restrict__ a_src1, const float* __restrict__ a_dst1,
                          const float* __restrict__ cb,
                          int* __restrict__ cursor, int2* __restrict__ es_se,
                          float* __restrict__ es_w) {
    int e = blockIdx.x * 256 + threadIdx.x;
    if (e >= NE) return;
    int s = src[e], d = dst[e];
    int pos = atomicAdd(&cursor[d], 1);
    float eav = ea[e];
    float4 as_ = *(const float4*)(a_src1 + s * 4);
    float4 ad_ = *(const float4*)(a_dst1 + d * 4);
    float lg0 = as_.x + ad_.x + eav * cb[56];
    float lg1 = as_.y + ad_.y + eav * cb[57];
    float lg2 = as_.z + ad_.z + eav * cb[58];
    float lg3 = as_.w + ad_.w + eav * cb[59];
    lg0 = lg0 >= 0.f ? lg0 : 0.2f * lg0;
    lg1 = lg1 >= 0.f ? lg1 : 0.2f * lg1;
    lg2 = lg2 >= 0.f ? lg2 : 0.2f * lg2;
    lg3 = lg3 >= 0.f ? lg3 : 0.2f * lg3;
    es_se[pos] = make_int2(s, __float_as_int(eav));
    *(float4*)(es_w + pos * 4) = make_float4(__expf(lg0), __expf(lg1), __expf(lg2), __expf(lg3));
}

// fused: conv1 reduce (m[4][8] per node, 8-edge batched) -> h -> a_src2/a_dst2 -> MFMA -> xh2 bf16
__global__ __launch_bounds__(256) void k_conv1red(
    const float* __restrict__ x, const float* __restrict__ W1, const float* __restrict__ b1,
    const float* __restrict__ cb, const int* __restrict__ offs,
    const int2* __restrict__ es_se, const float* __restrict__ es_w,
    const unsigned short* __restrict__ W2fr,
    unsigned short* __restrict__ xh2b, float* __restrict__ a_src2, float* __restrict__ a_dst2) {
    __shared__ __attribute__((aligned(16))) unsigned short hs[16][264];
    __shared__ float ms[4][32];
    int t = threadIdx.x, lane = t & 63, wid = t >> 6;
    float w1r[7][4], b1r[4], was2r[4], wad2r[4];
    #pragma unroll
    for (int k = 0; k < 7; ++k)
        #pragma unroll
        for (int h = 0; h < 4; ++h) w1r[k][h] = W1[k * 256 + h * 64 + lane];
    #pragma unroll
    for (int h = 0; h < 4; ++h) {
        b1r[h] = b1[h * 64 + lane];
        was2r[h] = cb[64 + h * 64 + lane];
        wad2r[h] = cb[320 + h * 64 + lane];
    }
    int eslot = lane >> 5, hh = (lane >> 3) & 3, kk = lane & 7;
    int n0 = blockIdx.x * 16;
    for (int nl = 0; nl < 4; ++nl) {
        int n = n0 + wid * 4 + nl;
        int o0 = offs[n], o1 = offs[n + 1];
        float m = 0.f;
        for (int j = o0; j < o1; j += 8) {
            int sl = 0; float wl = 0.f;
            if (lane < 8 && j + lane < o1) sl = es_se[j + lane].x;
            if (lane < 32 && j + (lane >> 2) < o1) wl = es_w[j * 4 + lane];
            #pragma unroll
            for (int p = 0; p < 4; ++p) {
                int s = __shfl(sl, p * 2 + eslot, 64);
                float w = __shfl(wl, (p * 2 + eslot) * 4 + hh, 64);
                float xv = (kk < 7) ? x[s * 7 + kk] : 1.f;
                m = fmaf(w, xv, m);
            }
        }
        m += __shfl_xor(m, 32, 64);
        if (lane < 32) ms[wid][lane] = m;
        bool has = o1 > o0;
        float ps = 0.f, pd = 0.f;
        #pragma unroll
        for (int h = 0; h < 4; ++h) {
            float z = ms[wid][h * 8 + 7];
            float a = 0.f;
            #pragma unroll
            for (int k = 0; k < 7; ++k) a += ms[wid][h * 8 + k] * w1r[k][h];
            float mm = (has ? a / z : 0.f) + b1r[h];
            float hv = mm > 0.f ? mm : (__expf(mm) - 1.f);
            ps += hv * was2r[h];
            pd += hv * wad2r[h];
            hs[wid * 4 + nl][h * 64 + lane] = f2bf(hv);
        }
        ps = wave_reduce_sum(ps);
        pd = wave_reduce_sum(pd);
        if (lane == 0) { a_src2[n] = ps; a_dst2[n] = pd; }
    }
    __syncthreads();
    // MFMA: xh2[16 nodes][64 ch]; wave wid owns column tile wid*16..+16
    f32x4 acc = {0.f, 0.f, 0.f, 0.f};
    int row = lane & 15, kg = lane >> 4;
    #pragma unroll
    for (int ks = 0; ks < 8; ++ks) {
        bf16x8 av = *(const bf16x8*)&hs[row][ks * 32 + kg * 8];
        bf16x8 bv = *(const bf16x8*)(W2fr + (((ks * 4 + wid) * 64) + lane) * 8);
        acc = __builtin_amdgcn_mfma_f32_16x16x32_bf16(av, bv, acc, 0, 0, 0);
    }
    #pragma unroll
    for (int i = 0; i < 4; ++i) {
        int r = kg * 4 + i;
        xh2b[(n0 + r) * 64 + wid * 16 + row] = f2bf(acc[i]);
    }
}

// conv2 normalization + per-source cluster coefficient table:
// wave handles 8 nodes (8 lanes each); two passes over the node's contiguous
// sorted-edge run: (1) z = sum of exp(leaky(logit)), (2) atomicAdd cs[src][c] += w/z.
__global__ __launch_bounds__(256) void k_znorm(
    const int2* __restrict__ es_se, const int* __restrict__ offs,
    const float* __restrict__ a_src2, const float* __restrict__ a_dst2,
    const int* __restrict__ assign, const float* __restrict__ cb,
    float* __restrict__ cs) {
    int t = threadIdx.x, lane = t & 63, wid = t >> 6;
    int g = lane >> 3, q = lane & 7;
    int n = (blockIdx.x * 4 + wid) * 8 + g;
    int o0 = offs[n], o1 = offs[n + 1];
    float adn = a_dst2[n];
    float c2 = cb[60];
    float z = 0.f;
    for (int j = o0 + q; j < o1; j += 8) {
        int2 se = es_se[j];
        float lg = a_src2[se.x] + adn + __int_as_float(se.y) * c2;
        lg = lg >= 0.f ? lg : 0.2f * lg;
        z += __expf(lg);
    }
    z += __shfl_xor(z, 1, 64);
    z += __shfl_xor(z, 2, 64);
    z += __shfl_xor(z, 4, 64);
    float rz = 1.f / z;          // no edges -> loop below doesn't run
    int c = assign[n];
    for (int j = o0 + q; j < o1; j += 8) {
        int2 se = es_se[j];
        float lg = a_src2[se.x] + adn + __int_as_float(se.y) * c2;
        lg = lg >= 0.f ? lg : 0.2f * lg;
        atomicAdd(&cs[se.x * 4 + c], __expf(lg) * rz);
    }
}

// coalesced pooling: cluster_sum[c][j] = sum_n cs[n][c] * xh2[n][j]; + counts/cf
__global__ __launch_bounds__(256) void k_pool(
    const unsigned short* __restrict__ xh2b, const float* __restrict__ cs,
    const int* __restrict__ assign, const float* __restrict__ x,
    float* __restrict__ gacc) {
    __shared__ float csum[264];
    int t = threadIdx.x, lane = t & 63, wid = t >> 6;
    for (int i = t; i < 264; i += 256) csum[i] = 0.f;
    __syncthreads();
    float f0 = 0.f, f1 = 0.f, f2 = 0.f, f3 = 0.f;
    float cnt = 0.f, cf = 0.f;
    int nw = gridDim.x * 4;
    for (int n = blockIdx.x * 4 + wid; n < NN; n += nw) {
        float v = bf2f(xh2b[n * 64 + lane]);
        float4 c4 = *(const float4*)(cs + n * 4);
        f0 = fmaf(c4.x, v, f0);
        f1 = fmaf(c4.y, v, f1);
        f2 = fmaf(c4.z, v, f2);
        f3 = fmaf(c4.w, v, f3);
        if (lane < 4) {
            int a = assign[n];
            if (a == lane) { cnt += 1.f; cf += x[n * 7 + 6]; }
        }
    }
    atomicAdd(&csum[0 * 64 + lane], f0);
    atomicAdd(&csum[1 * 64 + lane], f1);
    atomicAdd(&csum[2 * 64 + lane], f2);
    atomicAdd(&csum[3 * 64 + lane], f3);
    if (lane < 4) {
        atomicAdd(&csum[256 + lane], cnt);
        atomicAdd(&csum[260 + lane], cf);
    }
    __syncthreads();
    for (int i = t; i < 264; i += 256) atomicAdd(&gacc[i], csum[i]);
}

// final head: cluster means (+cnt*b2), actor MLP + softmax, critic MLP
__global__ void k_head(const float* __restrict__ gacc, const float* __restrict__ b2,
                       const float* __restrict__ A1, const float* __restrict__ ba1,
                       const float* __restrict__ A2, const float* __restrict__ ba2,
                       const float* __restrict__ C1, const float* __restrict__ bc1,
                       const float* __restrict__ C2, const float* __restrict__ bc2,
                       float* __restrict__ out) {
    __shared__ float zc[4][64];
    __shared__ float cfs[4];
    __shared__ float logits[4];
    int j = threadIdx.x; // 64
    float b2j = b2[j];
    #pragma unroll
    for (int c = 0; c < 4; ++c) {
        float cnt = gacc[256 + c];
        float den = fmaxf(cnt, 1.f);
        zc[c][j] = (cnt > 0.f) ? (gacc[c * 64 + j] + cnt * b2j) / den : 0.f;
        if (j == 0) cfs[c] = (cnt > 0.f) ? gacc[260 + c] / den : 0.f;
    }
    __syncthreads();
    #pragma unroll
    for (int c = 0; c < 4; ++c) {
        float tv = ba1[j];
        for (int k = 0; k < 64; ++k) tv += zc[c][k] * A1[k * 64 + j];
        tv += cfs[c] * A1[64 * 64 + j];
        tv = fmaxf(tv, 0.f);
        float s = wave_reduce_sum(tv * A2[j]);
        if (j == 0) logits[c] = s + ba2[0];
    }
    float vj = bc1[j];
    for (int k = 0; k < 256; ++k) vj += zc[k >> 6][k & 63] * C1[k * 64 + j];
    vj = fmaxf(vj, 0.f);
    float v = wave_reduce_sum(vj * C2[j]);
    __syncthreads();
    if (j == 0) {
        float m = fmaxf(fmaxf(logits[0], logits[1]), fmaxf(logits[2], logits[3]));
        float e0 = __expf(logits[0] - m), e1 = __expf(logits[1] - m);
        float e2 = __expf(logits[2] - m), e3 = __expf(logits[3] - m);
        float sum = e0 + e1 + e2 + e3;
        out[0] = e0 / sum; out[1] = e1 / sum; out[2] = e2 / sum; out[3] = e3 / sum;
        out[4] = v + bc2[0];
    }
    #pragma unroll
    for (int c = 0; c < 4; ++c) out[5 + c * 64 + j] = zc[c][j];
}

extern "C" void kernel_launch(void* const* d_in, const int* in_sizes, int n_in,
                              void* d_out, int out_size, void* d_ws, size_t ws_size,
                              hipStream_t stream) {
    const float* x    = (const float*)d_in[0];
    const int*   ei   = (const int*)d_in[1];
    const float* ea   = (const float*)d_in[2];
    const int*   asg  = (const int*)d_in[3];
    const float* W1   = (const float*)d_in[4];
    const float* as1  = (const float*)d_in[5];
    const float* ad1  = (const float*)d_in[6];
    const float* We1  = (const float*)d_in[7];
    const float* ae1  = (const float*)d_in[8];
    const float* b1   = (const float*)d_in[9];
    const float* W2   = (const float*)d_in[10];
    const float* as2  = (const float*)d_in[11];
    const float* ad2  = (const float*)d_in[12];
    const float* We2  = (const float*)d_in[13];
    const float* ae2  = (const float*)d_in[14];
    const float* b2   = (const float*)d_in[15];
    const float* A1   = (const float*)d_in[16];
    const float* ba1  = (const float*)d_in[17];
    const float* A2   = (const float*)d_in[18];
    const float* ba2  = (const float*)d_in[19];
    const float* C1   = (const float*)d_in[20];
    const float* bc1  = (const float*)d_in[21];
    const float* C2   = (const float*)d_in[22];
    const float* bc2  = (const float*)d_in[23];
    const int* src = ei;
    const int* dst = ei + NE;

    char* w = (char*)d_ws;
    size_t off = 0;
    auto alloc = [&](size_t bytes) -> void* {
        void* p = w + off;
        off += (bytes + 255) & ~(size_t)255;
        return p;
    };
    float* a_src1 = (float*)alloc(NN * 4 * sizeof(float));
    float* a_dst1 = (float*)alloc(NN * 4 * sizeof(float));
    float* a_src2 = (float*)alloc(NN * sizeof(float));
    float* a_dst2 = (float*)alloc(NN * sizeof(float));
    int*   hist   = (int*)alloc(NN * sizeof(int));
    int*   offs   = (int*)alloc((NN + 1) * sizeof(int));
    int*   cursor = (int*)alloc(NN * sizeof(int));
    int*   bsum   = (int*)alloc(128 * sizeof(int));
    int*   bexcl  = (int*)alloc(128 * sizeof(int));
    int2*  es_se  = (int2*)alloc(NE * sizeof(int2));
    float* es_w   = (float*)alloc(NE * 4 * sizeof(float));
    float* cs     = (float*)alloc(NN * 4 * sizeof(float));
    unsigned short* xh2b = (unsigned short*)alloc(NN * 64 * sizeof(unsigned short));
    unsigned short* W2fr = (unsigned short*)alloc(16384 * sizeof(unsigned short));
    float* cb     = (float*)alloc(576 * sizeof(float));
    float* gacc   = (float*)alloc(264 * sizeof(float));
    (void)ws_size; (void)n_in; (void)in_sizes; (void)out_size;

    hipMemsetAsync(hist, 0, NN * sizeof(int), stream);
    hipMemsetAsync(cs, 0, NN * 4 * sizeof(float), stream);
    hipMemsetAsync(gacc, 0, 264 * sizeof(float), stream);

    k_pre<<<65, 256, 0, stream>>>(W1, as1, ad1, We1, ae1, We2, ae2, W2, as2, ad2, cb, W2fr);
    k_node1<<<(NN + 255) / 256, 256, 0, stream>>>(x, cb, a_src1, a_dst1);
    k_hist<<<(NE / 4 + 255) / 256, 256, 0, stream>>>(dst, hist);
    k_scanA<<<98, 1024, 0, stream>>>(hist, bsum);
    k_scanB<<<1, 128, 0, stream>>>(bsum, bexcl);
    k_scanC<<<98, 1024, 0, stream>>>(hist, bexcl, offs, cursor);
    k_scatter<<<(NE + 255) / 256, 256, 0, stream>>>(src, dst, ea, a_src1, a_dst1, cb,
                                                    cursor, es_se, es_w);
    k_conv1red<<<NN / 16, 256, 0, stream>>>(x, W1, b1, cb, offs, es_se, es_w, W2fr,
                                            xh2b, a_src2, a_dst2);
    k_znorm<<<NN / 32, 256, 0, stream>>>(es_se, offs, a_src2, a_dst2, asg, cb, cs);
    k_pool<<<256, 256, 0, stream>>>(xh2b, cs, asg, x, gacc);
    k_head<<<1, 64, 0, stream>>>(gacc, b2, A1, ba1, A2, ba2, C1, bc1, C2, bc2, (float*)d_out);
}